// Round 4
// baseline (708.432 us; speedup 1.0000x reference)
//
#include <hip/hip_runtime.h>
#include <hip/hip_bf16.h>

// GraphSAGE 2-layer, N=100000, E=1.6M, D=128. ALL I/O FLOAT32.
// (bf16 tolerance mode = harness allows bf16 MFMA compute; storage is f32.)
//
// h1 staged as f32 in d_out; gemm2 overwrites it (each wave reads only its
// own 32 rows, all reads precede its writes -> safe self-alias).
//
// ws (~33.2 MB): deg/offs/cursor 3x400KB, partials, sortedSrc 6.4MB,
// Aagg (bf16 [N,128]) 25.6MB.
//
// Pipeline: memset deg -> hist -> scan(3 pass) -> bucket scatter (CSR) ->
//   agg(x f32 -> Aagg bf16) -> gemm1([Aagg|x]@[Wn1;Ws1]^T+b, relu -> h1 f32)
//   agg(h1 f32 -> Aagg bf16) -> gemm2([Aagg|h1]@[Wn2;Ws2]^T+b -> d_out f32)

typedef __attribute__((ext_vector_type(8))) short short8;
typedef __attribute__((ext_vector_type(4))) float float4_;

__device__ __forceinline__ unsigned short f2bf(float f) {
    unsigned int u = __float_as_uint(f);
    unsigned int r = (u + 0x7FFFu + ((u >> 16) & 1u)) >> 16;
    return (unsigned short)r;
}

// ---------------- degree histogram ----------------
__global__ void hist_kernel(const int* __restrict__ dst, int E, int* __restrict__ deg) {
    int t = blockIdx.x * blockDim.x + threadIdx.x;
    if (t < E) atomicAdd(&deg[dst[t]], 1);
}

// ---------------- scan (3-pass) ----------------
#define SCHUNK 4096
__global__ __launch_bounds__(256) void scan1(const int* __restrict__ deg, int Nn,
                                             int* __restrict__ partial) {
    __shared__ int sw[4];
    int tid = threadIdx.x;
    int base = blockIdx.x * SCHUNK + tid * 16;
    int s = 0;
    for (int i = 0; i < 16; i++) {
        int idx = base + i;
        if (idx < Nn) s += deg[idx];
    }
    for (int off = 32; off; off >>= 1) s += __shfl_down(s, off, 64);
    if ((tid & 63) == 0) sw[tid >> 6] = s;
    __syncthreads();
    if (tid == 0) partial[blockIdx.x] = sw[0] + sw[1] + sw[2] + sw[3];
}

__global__ void scan2(const int* __restrict__ partial, int nb, int* __restrict__ partialOff) {
    if (threadIdx.x == 0 && blockIdx.x == 0) {
        int run = 0;
        for (int b = 0; b < nb; b++) {
            int t = partial[b];
            partialOff[b] = run;
            run += t;
        }
    }
}

__global__ __launch_bounds__(256) void scan3(const int* __restrict__ deg, int Nn,
                                             const int* __restrict__ partialOff,
                                             int* __restrict__ offs, int* __restrict__ cursor) {
    __shared__ int sd[256];
    int tid = threadIdx.x;
    int base = blockIdx.x * SCHUNK + tid * 16;
    int v[16];
    int tot = 0;
    for (int i = 0; i < 16; i++) {
        int idx = base + i;
        v[i] = (idx < Nn) ? deg[idx] : 0;
        tot += v[i];
    }
    sd[tid] = tot;
    __syncthreads();
    for (int off = 1; off < 256; off <<= 1) {
        int x = sd[tid];
        int y = (tid >= off) ? sd[tid - off] : 0;
        __syncthreads();
        sd[tid] = x + y;
        __syncthreads();
    }
    int excl = sd[tid] - tot;
    int run = partialOff[blockIdx.x] + excl;
    for (int i = 0; i < 16; i++) {
        int idx = base + i;
        if (idx < Nn) {
            offs[idx] = run;
            cursor[idx] = run;
        }
        run += v[i];
    }
}

// ---------------- bucket scatter ----------------
__global__ void scatter_kernel(const int* __restrict__ src, const int* __restrict__ dst, int E,
                               int* __restrict__ cursor, int* __restrict__ sortedSrc) {
    int t = blockIdx.x * blockDim.x + threadIdx.x;
    if (t < E) {
        int p = atomicAdd(&cursor[dst[t]], 1);
        sortedSrc[p] = src[t];
    }
}

// ---------------- mean aggregation, f32 source -> bf16 dst (wave/node) ------
// srcFeats: [N,128] f32. dst: [N,128] bf16 viewed as u32 [N,64].
__global__ __launch_bounds__(256) void agg_kernel(
    const float* __restrict__ srcFeats,
    const int* __restrict__ deg, const int* __restrict__ offs,
    const int* __restrict__ sortedSrc,
    unsigned int* __restrict__ dst, int Nn, int Emax) {
    int wave = threadIdx.x >> 6, lane = threadIdx.x & 63;
    int n = blockIdx.x * 4 + wave;
    if (n >= Nn) return;
    int d = deg[n], st = offs[n];
    if (d < 0) d = 0;
    if (st < 0 || st > Emax - d) { st = 0; d = 0; }  // defensive
    float a0 = 0.f, a1 = 0.f;
    for (int j = 0; j < d; j++) {
        int s = sortedSrc[st + j];
        if ((unsigned)s >= (unsigned)Nn) s = 0;  // defensive: finite, not wild
        const float2* p = (const float2*)(srcFeats + (size_t)s * 128);
        float2 v = p[lane];
        a0 += v.x;
        a1 += v.y;
    }
    float inv = 1.0f / (float)max(d, 1);
    unsigned int lo = f2bf(a0 * inv);
    unsigned int hi = f2bf(a1 * inv);
    dst[(size_t)n * 64 + lane] = lo | (hi << 16);
}

// ---------------- fused GEMM: out = act([Aagg|Aself] @ [Wn;Ws]^T + bn+bs) --
// Aagg: [N,128] bf16. Aself: [N,128] f32 (converted to bf16 on the fly).
// Wn,Ws,bn,bs: f32. Out: [N,128] f32. MFMA 16x16x32 bf16.
// Block: 256 thr = 4 waves, 32 rows/wave -> 128 rows/block.
// Combined B (256x128) converted f32->bf16, pre-swizzled to frag order in LDS.
// Out may alias Aself (h1 in d_out): each wave reads only its own 32 rows
// during the K loop, then writes those rows -> safe. (No __restrict__ there.)
__global__ __launch_bounds__(256) void gemm_kernel(
    const unsigned short* __restrict__ Aagg, const float* Aself,
    const float* __restrict__ Wn, const float* __restrict__ Ws,
    const float* __restrict__ bn, const float* __restrict__ bs,
    float* Out, int relu, int Nrows) {
    __shared__ unsigned short ldsB[8 * 8 * 64 * 8];  // [kt][nt][lane][8] = 64 KB
    __shared__ float biasS[128];
    int tid = threadIdx.x;

    // frag(kt,nt,lane)[j] = B[kt*32+(lane>>4)*8+j][nt*16+(lane&15)]
    // B[k][o] = k<128 ? Wn[o][k] : Ws[o][k-128] (8 consecutive f32 in W row)
    for (int i = 0; i < 16; i++) {
        int fi = tid + 256 * i;
        int kt = fi >> 9;
        int nt = (fi >> 6) & 7;
        int lane = fi & 63;
        int o = nt * 16 + (lane & 15);
        int k = kt * 32 + (lane >> 4) * 8;
        const float* srcp = (k < 128) ? (Wn + o * 128 + k) : (Ws + o * 128 + (k - 128));
        short8 v;
#pragma unroll
        for (int j = 0; j < 8; j++) v[j] = (short)f2bf(srcp[j]);
        *(short8*)(ldsB + (size_t)fi * 8) = v;
    }
    if (tid < 128) biasS[tid] = bn[tid] + bs[tid];
    __syncthreads();

    int wave = tid >> 6, lane = tid & 63;
    int quad = lane >> 4, mr = lane & 15;
    int rowBase = blockIdx.x * 128 + wave * 32;

    float4_ acc[2][8];
    float4_ z = {0.f, 0.f, 0.f, 0.f};
    for (int mt = 0; mt < 2; mt++)
        for (int nt = 0; nt < 8; nt++) acc[mt][nt] = z;

    for (int kt = 0; kt < 8; kt++) {
        int kk = (kt & 3) * 32 + quad * 8;
        short8 a[2];
        for (int mt = 0; mt < 2; mt++) {
            int row = rowBase + mt * 16 + mr;
            if (row >= Nrows) row = Nrows - 1;  // in-bounds; result discarded
            if (kt < 4) {
                a[mt] = *(const short8*)(Aagg + (size_t)row * 128 + kk);
            } else {
                const float* p = Aself + (size_t)row * 128 + kk;
                float4_ f0 = *(const float4_*)p;
                float4_ f1 = *(const float4_*)(p + 4);
                short8 t;
#pragma unroll
                for (int j = 0; j < 4; j++) {
                    t[j] = (short)f2bf(f0[j]);
                    t[4 + j] = (short)f2bf(f1[j]);
                }
                a[mt] = t;
            }
        }
        for (int nt = 0; nt < 8; nt++) {
            short8 b = *(const short8*)(ldsB + ((size_t)(kt * 8 + nt) * 64 + lane) * 8);
            acc[0][nt] = __builtin_amdgcn_mfma_f32_16x16x32_bf16(a[0], b, acc[0][nt], 0, 0, 0);
            acc[1][nt] = __builtin_amdgcn_mfma_f32_16x16x32_bf16(a[1], b, acc[1][nt], 0, 0, 0);
        }
    }

    // C/D layout: col = lane&15, row = (lane>>4)*4 + reg
    for (int mt = 0; mt < 2; mt++) {
        for (int nt = 0; nt < 8; nt++) {
            int col = nt * 16 + mr;
            float bv = biasS[col];
            for (int r = 0; r < 4; r++) {
                int row = rowBase + mt * 16 + quad * 4 + r;
                if (row < Nrows) {
                    float v = acc[mt][nt][r] + bv;
                    if (relu) v = fmaxf(v, 0.f);
                    Out[(size_t)row * 128 + col] = v;
                }
            }
        }
    }
}

extern "C" void kernel_launch(void* const* d_in, const int* in_sizes, int n_in,
                              void* d_out, int out_size, void* d_ws, size_t ws_size,
                              hipStream_t stream) {
    const float* x = (const float*)d_in[0];
    const int* ei = (const int*)d_in[1];
    const float* Wn1 = (const float*)d_in[2];
    const float* bn1 = (const float*)d_in[3];
    const float* Ws1 = (const float*)d_in[4];
    const float* bs1 = (const float*)d_in[5];
    const float* Wn2 = (const float*)d_in[6];
    const float* bn2 = (const float*)d_in[7];
    const float* Ws2 = (const float*)d_in[8];
    const float* bs2 = (const float*)d_in[9];

    const int N = in_sizes[0] / 128;
    const int E = in_sizes[1] / 2;
    const int* srcI = ei;
    const int* dstI = ei + E;

    // workspace layout (~33.2 MB total)
    char* ws = (char*)d_ws;
    size_t off = 0;
    auto alloc = [&](size_t bytes) -> void* {
        void* p = ws + off;
        off += (bytes + 255) & ~(size_t)255;
        return p;
    };
    int* deg = (int*)alloc((size_t)N * 4);
    int* offs = (int*)alloc((size_t)N * 4);
    int* cursor = (int*)alloc((size_t)N * 4);
    int* partial = (int*)alloc(64 * 4);
    int* partialOff = (int*)alloc(64 * 4);
    int* sortedSrc = (int*)alloc((size_t)E * 4);
    unsigned short* Aagg = (unsigned short*)alloc((size_t)N * 128 * 2);
    (void)ws_size;

    float* h1 = (float*)d_out;  // f32 h1 staged in d_out, overwritten by gemm2

    hipMemsetAsync(deg, 0, (size_t)N * 4, stream);
    hist_kernel<<<(E + 255) / 256, 256, 0, stream>>>(dstI, E, deg);
    int nb = (N + SCHUNK - 1) / SCHUNK;
    scan1<<<nb, 256, 0, stream>>>(deg, N, partial);
    scan2<<<1, 64, 0, stream>>>(partial, nb, partialOff);
    scan3<<<nb, 256, 0, stream>>>(deg, N, partialOff, offs, cursor);
    scatter_kernel<<<(E + 255) / 256, 256, 0, stream>>>(srcI, dstI, E, cursor, sortedSrc);

    // layer 1
    agg_kernel<<<(N + 3) / 4, 256, 0, stream>>>(x, deg, offs, sortedSrc,
                                                (unsigned int*)Aagg, N, E);
    gemm_kernel<<<(N + 127) / 128, 256, 0, stream>>>(Aagg, x, Wn1, Ws1, bn1, bs1, h1, 1, N);
    // layer 2
    agg_kernel<<<(N + 3) / 4, 256, 0, stream>>>(h1, deg, offs, sortedSrc,
                                                (unsigned int*)Aagg, N, E);
    gemm_kernel<<<(N + 127) / 128, 256, 0, stream>>>(Aagg, h1, Wn2, Ws2, bn2, bs2,
                                                     (float*)d_out, 0, N);
}

// Round 5
// 532.021 us; speedup vs baseline: 1.3316x; 1.3316x over previous
//
#include <hip/hip_runtime.h>
#include <hip/hip_bf16.h>

// GraphSAGE 2-layer, N=100000, E=1.6M, D=128. f32 I/O, bf16 MFMA compute.
//
// R5: gather traffic halved (bf16 feature gathers) + 8-deep gather pipelining.
//   Layout A (ws >= ~84.4 MB): xb=bf16(x), h1b=bf16 h1, Aagg bf16; both agg
//   passes gather bf16 (256 B/row). Fallback B (round-4 proven, ~33.2 MB):
//   f32 gathers, h1 f32 staged in d_out.
//
// Pipeline: memset deg -> hist -> scan(3) -> scatter (CSR) -> [convert x]
//   -> agg1 -> gemm1(relu) -> agg2 -> gemm2 -> d_out f32.

typedef __attribute__((ext_vector_type(8))) short short8;
typedef __attribute__((ext_vector_type(4))) float float4_;

__device__ __forceinline__ unsigned short f2bf(float f) {
    unsigned int u = __float_as_uint(f);
    unsigned int r = (u + 0x7FFFu + ((u >> 16) & 1u)) >> 16;
    return (unsigned short)r;
}

// ---------------- degree histogram ----------------
__global__ void hist_kernel(const int* __restrict__ dst, int E, int* __restrict__ deg) {
    int t = blockIdx.x * blockDim.x + threadIdx.x;
    if (t < E) atomicAdd(&deg[dst[t]], 1);
}

// ---------------- scan (3-pass) ----------------
#define SCHUNK 4096
__global__ __launch_bounds__(256) void scan1(const int* __restrict__ deg, int Nn,
                                             int* __restrict__ partial) {
    __shared__ int sw[4];
    int tid = threadIdx.x;
    int base = blockIdx.x * SCHUNK + tid * 16;
    int s = 0;
    for (int i = 0; i < 16; i++) {
        int idx = base + i;
        if (idx < Nn) s += deg[idx];
    }
    for (int off = 32; off; off >>= 1) s += __shfl_down(s, off, 64);
    if ((tid & 63) == 0) sw[tid >> 6] = s;
    __syncthreads();
    if (tid == 0) partial[blockIdx.x] = sw[0] + sw[1] + sw[2] + sw[3];
}

__global__ void scan2(const int* __restrict__ partial, int nb, int* __restrict__ partialOff) {
    if (threadIdx.x == 0 && blockIdx.x == 0) {
        int run = 0;
        for (int b = 0; b < nb; b++) {
            int t = partial[b];
            partialOff[b] = run;
            run += t;
        }
    }
}

__global__ __launch_bounds__(256) void scan3(const int* __restrict__ deg, int Nn,
                                             const int* __restrict__ partialOff,
                                             int* __restrict__ offs, int* __restrict__ cursor) {
    __shared__ int sd[256];
    int tid = threadIdx.x;
    int base = blockIdx.x * SCHUNK + tid * 16;
    int v[16];
    int tot = 0;
    for (int i = 0; i < 16; i++) {
        int idx = base + i;
        v[i] = (idx < Nn) ? deg[idx] : 0;
        tot += v[i];
    }
    sd[tid] = tot;
    __syncthreads();
    for (int off = 1; off < 256; off <<= 1) {
        int x = sd[tid];
        int y = (tid >= off) ? sd[tid - off] : 0;
        __syncthreads();
        sd[tid] = x + y;
        __syncthreads();
    }
    int excl = sd[tid] - tot;
    int run = partialOff[blockIdx.x] + excl;
    for (int i = 0; i < 16; i++) {
        int idx = base + i;
        if (idx < Nn) {
            offs[idx] = run;
            cursor[idx] = run;
        }
        run += v[i];
    }
}

// ---------------- bucket scatter ----------------
__global__ void scatter_kernel(const int* __restrict__ src, const int* __restrict__ dst, int E,
                               int* __restrict__ cursor, int* __restrict__ sortedSrc) {
    int t = blockIdx.x * blockDim.x + threadIdx.x;
    if (t < E) {
        int p = atomicAdd(&cursor[dst[t]], 1);
        sortedSrc[p] = src[t];
    }
}

// ---------------- f32 [N,128] -> packed bf16 u32 [N,64] ----------------
__global__ __launch_bounds__(256) void cvt_kernel(const float* __restrict__ in,
                                                  unsigned int* __restrict__ out, int n2) {
    int t = blockIdx.x * 256 + threadIdx.x;
    if (t < n2) {
        float2 v = ((const float2*)in)[t];
        out[t] = (unsigned)f2bf(v.x) | ((unsigned)f2bf(v.y) << 16);
    }
}

// ---------------- mean agg, bf16 source (wave/node, 8-deep pipeline) --------
// srcFeats: [N,64] u32 (packed bf16). dst likewise.
__global__ __launch_bounds__(256) void agg_bf16_kernel(
    const unsigned int* __restrict__ srcFeats,
    const int* __restrict__ deg, const int* __restrict__ offs,
    const int* __restrict__ sortedSrc,
    unsigned int* __restrict__ dst, int Nn) {
    int wave = threadIdx.x >> 6, lane = threadIdx.x & 63;
    int n = blockIdx.x * 4 + wave;
    if (n >= Nn) return;
    int d = deg[n], st = offs[n];
    float a0 = 0.f, a1 = 0.f;
    int j = 0;
    for (; j + 8 <= d; j += 8) {
        int s[8];
#pragma unroll
        for (int u = 0; u < 8; u++) s[u] = sortedSrc[st + j + u];
        unsigned int uu[8];
#pragma unroll
        for (int u = 0; u < 8; u++) uu[u] = srcFeats[(size_t)s[u] * 64 + lane];
#pragma unroll
        for (int u = 0; u < 8; u++) {
            a0 += __uint_as_float(uu[u] << 16);
            a1 += __uint_as_float(uu[u] & 0xFFFF0000u);
        }
    }
    for (; j < d; j++) {
        int s = sortedSrc[st + j];
        unsigned int u = srcFeats[(size_t)s * 64 + lane];
        a0 += __uint_as_float(u << 16);
        a1 += __uint_as_float(u & 0xFFFF0000u);
    }
    float inv = 1.0f / (float)max(d, 1);
    dst[(size_t)n * 64 + lane] = (unsigned)f2bf(a0 * inv) | ((unsigned)f2bf(a1 * inv) << 16);
}

// ---------------- mean agg, f32 source (fallback layout B) ------------------
__global__ __launch_bounds__(256) void agg_f32_kernel(
    const float* __restrict__ srcFeats,
    const int* __restrict__ deg, const int* __restrict__ offs,
    const int* __restrict__ sortedSrc,
    unsigned int* __restrict__ dst, int Nn) {
    int wave = threadIdx.x >> 6, lane = threadIdx.x & 63;
    int n = blockIdx.x * 4 + wave;
    if (n >= Nn) return;
    int d = deg[n], st = offs[n];
    float a0 = 0.f, a1 = 0.f;
    int j = 0;
    for (; j + 4 <= d; j += 4) {
        int s[4];
#pragma unroll
        for (int u = 0; u < 4; u++) s[u] = sortedSrc[st + j + u];
        float2 v[4];
#pragma unroll
        for (int u = 0; u < 4; u++) v[u] = ((const float2*)(srcFeats + (size_t)s[u] * 128))[lane];
#pragma unroll
        for (int u = 0; u < 4; u++) {
            a0 += v[u].x;
            a1 += v[u].y;
        }
    }
    for (; j < d; j++) {
        int s = sortedSrc[st + j];
        float2 v = ((const float2*)(srcFeats + (size_t)s * 128))[lane];
        a0 += v.x;
        a1 += v.y;
    }
    float inv = 1.0f / (float)max(d, 1);
    dst[(size_t)n * 64 + lane] = (unsigned)f2bf(a0 * inv) | ((unsigned)f2bf(a1 * inv) << 16);
}

// ---------------- fused GEMM: out = act([Aagg|Aself] @ [Wn;Ws]^T + bn+bs) --
// Aagg: [N,128] bf16. Aself: bf16 (selfF32=0) or f32 (selfF32=1).
// Out: bf16 (outBf16=1) or f32. MFMA 16x16x32 bf16; 4 waves, 128 rows/block.
// Combined B (256x128) f32->bf16, pre-swizzled to fragment order in LDS.
// Out may alias Aself (fallback layer 2): each wave reads only its own 32
// rows before writing them -> safe. (No __restrict__ on Aself/Out.)
__global__ __launch_bounds__(256) void gemm_kernel(
    const unsigned short* __restrict__ Aagg, const void* Aself,
    const float* __restrict__ Wn, const float* __restrict__ Ws,
    const float* __restrict__ bn, const float* __restrict__ bs,
    void* Out, int relu, int selfF32, int outBf16, int Nrows) {
    __shared__ unsigned short ldsB[8 * 8 * 64 * 8];  // 64 KB
    __shared__ float biasS[128];
    int tid = threadIdx.x;

    // frag(kt,nt,lane)[j] = B[kt*32+(lane>>4)*8+j][nt*16+(lane&15)]
    for (int i = 0; i < 16; i++) {
        int fi = tid + 256 * i;
        int kt = fi >> 9;
        int nt = (fi >> 6) & 7;
        int lane = fi & 63;
        int o = nt * 16 + (lane & 15);
        int k = kt * 32 + (lane >> 4) * 8;
        const float* srcp = (k < 128) ? (Wn + o * 128 + k) : (Ws + o * 128 + (k - 128));
        short8 v;
#pragma unroll
        for (int j = 0; j < 8; j++) v[j] = (short)f2bf(srcp[j]);
        *(short8*)(ldsB + (size_t)fi * 8) = v;
    }
    if (tid < 128) biasS[tid] = bn[tid] + bs[tid];
    __syncthreads();

    int wave = tid >> 6, lane = tid & 63;
    int quad = lane >> 4, mr = lane & 15;
    int rowBase = blockIdx.x * 128 + wave * 32;

    float4_ acc[2][8];
    float4_ z = {0.f, 0.f, 0.f, 0.f};
    for (int mt = 0; mt < 2; mt++)
        for (int nt = 0; nt < 8; nt++) acc[mt][nt] = z;

    for (int kt = 0; kt < 8; kt++) {
        int kk = (kt & 3) * 32 + quad * 8;
        short8 a[2];
        for (int mt = 0; mt < 2; mt++) {
            int row = rowBase + mt * 16 + mr;
            if (row >= Nrows) row = Nrows - 1;  // in-bounds; result discarded
            if (kt < 4) {
                a[mt] = *(const short8*)(Aagg + (size_t)row * 128 + kk);
            } else if (selfF32) {
                const float* p = (const float*)Aself + (size_t)row * 128 + kk;
                float4_ f0 = *(const float4_*)p;
                float4_ f1 = *(const float4_*)(p + 4);
                short8 t;
#pragma unroll
                for (int j = 0; j < 4; j++) {
                    t[j] = (short)f2bf(f0[j]);
                    t[4 + j] = (short)f2bf(f1[j]);
                }
                a[mt] = t;
            } else {
                a[mt] = *(const short8*)((const unsigned short*)Aself + (size_t)row * 128 + kk);
            }
        }
        for (int nt = 0; nt < 8; nt++) {
            short8 b = *(const short8*)(ldsB + ((size_t)(kt * 8 + nt) * 64 + lane) * 8);
            acc[0][nt] = __builtin_amdgcn_mfma_f32_16x16x32_bf16(a[0], b, acc[0][nt], 0, 0, 0);
            acc[1][nt] = __builtin_amdgcn_mfma_f32_16x16x32_bf16(a[1], b, acc[1][nt], 0, 0, 0);
        }
    }

    // C/D layout: col = lane&15, row = (lane>>4)*4 + reg
    for (int mt = 0; mt < 2; mt++) {
        for (int nt = 0; nt < 8; nt++) {
            int col = nt * 16 + mr;
            float bv = biasS[col];
            for (int r = 0; r < 4; r++) {
                int row = rowBase + mt * 16 + quad * 4 + r;
                if (row < Nrows) {
                    float v = acc[mt][nt][r] + bv;
                    if (relu) v = fmaxf(v, 0.f);
                    if (outBf16)
                        ((unsigned short*)Out)[(size_t)row * 128 + col] = f2bf(v);
                    else
                        ((float*)Out)[(size_t)row * 128 + col] = v;
                }
            }
        }
    }
}

extern "C" void kernel_launch(void* const* d_in, const int* in_sizes, int n_in,
                              void* d_out, int out_size, void* d_ws, size_t ws_size,
                              hipStream_t stream) {
    const float* x = (const float*)d_in[0];
    const int* ei = (const int*)d_in[1];
    const float* Wn1 = (const float*)d_in[2];
    const float* bn1 = (const float*)d_in[3];
    const float* Ws1 = (const float*)d_in[4];
    const float* bs1 = (const float*)d_in[5];
    const float* Wn2 = (const float*)d_in[6];
    const float* bn2 = (const float*)d_in[7];
    const float* Ws2 = (const float*)d_in[8];
    const float* bs2 = (const float*)d_in[9];

    const int N = in_sizes[0] / 128;
    const int E = in_sizes[1] / 2;
    const int* srcI = ei;
    const int* dstI = ei + E;

    char* ws = (char*)d_ws;
    size_t off = 0;
    auto alloc = [&](size_t bytes) -> void* {
        void* p = ws + off;
        off += (bytes + 255) & ~(size_t)255;
        return p;
    };
    int* deg = (int*)alloc((size_t)N * 4);
    int* offs = (int*)alloc((size_t)N * 4);
    int* cursor = (int*)alloc((size_t)N * 4);
    int* partial = (int*)alloc(64 * 4);
    int* partialOff = (int*)alloc(64 * 4);
    int* sortedSrc = (int*)alloc((size_t)E * 4);
    unsigned short* Aagg = (unsigned short*)alloc((size_t)N * 128 * 2);
    size_t baseNeed = off;
    // Layout A extras (bf16 gather sources)
    size_t bf16Buf = ((size_t)N * 128 * 2 + 255) & ~(size_t)255;
    bool bigWs = (ws_size >= baseNeed + 2 * bf16Buf);
    unsigned int* xb = nullptr;
    unsigned short* h1b = nullptr;
    if (bigWs) {
        xb = (unsigned int*)alloc((size_t)N * 128 * 2);
        h1b = (unsigned short*)alloc((size_t)N * 128 * 2);
    }

    // CSR build
    hipMemsetAsync(deg, 0, (size_t)N * 4, stream);
    hist_kernel<<<(E + 255) / 256, 256, 0, stream>>>(dstI, E, deg);
    int nb = (N + SCHUNK - 1) / SCHUNK;
    scan1<<<nb, 256, 0, stream>>>(deg, N, partial);
    scan2<<<1, 64, 0, stream>>>(partial, nb, partialOff);
    scan3<<<nb, 256, 0, stream>>>(deg, N, partialOff, offs, cursor);
    scatter_kernel<<<(E + 255) / 256, 256, 0, stream>>>(srcI, dstI, E, cursor, sortedSrc);

    int aggBlocks = (N + 3) / 4;
    int gemmBlocks = (N + 127) / 128;

    if (bigWs) {
        // Layout A: all gathers bf16 (256 B/row)
        int n2 = N * 64;
        cvt_kernel<<<(n2 + 255) / 256, 256, 0, stream>>>(x, xb, n2);
        agg_bf16_kernel<<<aggBlocks, 256, 0, stream>>>(xb, deg, offs, sortedSrc,
                                                       (unsigned int*)Aagg, N);
        gemm_kernel<<<gemmBlocks, 256, 0, stream>>>(Aagg, xb, Wn1, Ws1, bn1, bs1, h1b,
                                                    1, 0, 1, N);
        agg_bf16_kernel<<<aggBlocks, 256, 0, stream>>>((const unsigned int*)h1b, deg, offs,
                                                       sortedSrc, (unsigned int*)Aagg, N);
        gemm_kernel<<<gemmBlocks, 256, 0, stream>>>(Aagg, h1b, Wn2, Ws2, bn2, bs2, d_out,
                                                    0, 0, 0, N);
    } else {
        // Layout B (round-4 proven): f32 gathers, h1 f32 staged in d_out
        float* h1 = (float*)d_out;
        agg_f32_kernel<<<aggBlocks, 256, 0, stream>>>(x, deg, offs, sortedSrc,
                                                      (unsigned int*)Aagg, N);
        gemm_kernel<<<gemmBlocks, 256, 0, stream>>>(Aagg, x, Wn1, Ws1, bn1, bs1, h1,
                                                    1, 1, 0, N);
        agg_f32_kernel<<<aggBlocks, 256, 0, stream>>>(h1, deg, offs, sortedSrc,
                                                      (unsigned int*)Aagg, N);
        gemm_kernel<<<gemmBlocks, 256, 0, stream>>>(Aagg, h1, Wn2, Ws2, bn2, bs2, d_out,
                                                    0, 1, 0, N);
    }
}

// Round 6
// 383.558 us; speedup vs baseline: 1.8470x; 1.3871x over previous
//
#include <hip/hip_runtime.h>
#include <hip/hip_bf16.h>

// GraphSAGE 2-layer, N=100000, E=1.6M, D=128. f32 I/O, bf16 MFMA compute.
//
// R6: CSR build rebuilt around dense-write bucket partition.
//   Old: hist(1.6M random atomics) + 3-pass scan + scatter(1.6M random 4B
//        writes -> 105 MB writeback, 127 us).
//   New: bucket_count -> bucket_scan -> partition (LDS-batched, contiguous
//        runs) -> csr_build (per-bucket LDS hist+scan+scatter; deg/offs/
//        sortedSrc all written dense). bucketBuf aliases Aagg (dead until
//        agg1), so footprint ~84.0 MB (<= R5's accepted 84.4 MB).
//
// Pipeline: memset bucketCnt -> bucket_count -> bucket_scan -> partition ->
//   csr_build -> cvt(x->bf16) -> agg1 -> gemm1(relu->h1b bf16) -> agg2 ->
//   gemm2 -> d_out f32.  Fallback layout B (small ws): f32 gathers, h1 in
//   d_out.

typedef __attribute__((ext_vector_type(8))) short short8;
typedef __attribute__((ext_vector_type(4))) float float4_;

#define NBMAX 512  // max buckets (256 nodes each) -> N <= 131072

__device__ __forceinline__ unsigned short f2bf(float f) {
    unsigned int u = __float_as_uint(f);
    unsigned int r = (u + 0x7FFFu + ((u >> 16) & 1u)) >> 16;
    return (unsigned short)r;
}

// ---------------- phase 1a: bucket histogram (bucket = dst >> 8) -----------
__global__ __launch_bounds__(256) void bucket_count(const int* __restrict__ dst, int E, int NB,
                                                    int* __restrict__ bucketCnt) {
    __shared__ int h[NBMAX];
    int tid = threadIdx.x;
    for (int b = tid; b < NB; b += 256) h[b] = 0;
    __syncthreads();
    int base = blockIdx.x * 4096;
    for (int i = 0; i < 16; i++) {
        int e = base + i * 256 + tid;
        if (e < E) atomicAdd(&h[dst[e] >> 8], 1);
    }
    __syncthreads();
    for (int b = tid; b < NB; b += 256)
        if (h[b]) atomicAdd(&bucketCnt[b], h[b]);
}

// ---------------- phase 1b: scan bucket counts (1 block) -------------------
__global__ __launch_bounds__(512) void bucket_scan(const int* __restrict__ bucketCnt, int NB,
                                                   int* __restrict__ bucketOffs,
                                                   int* __restrict__ bucketCur) {
    __shared__ int sd[512];
    int t = threadIdx.x;
    int v = (t < NB) ? bucketCnt[t] : 0;
    sd[t] = v;
    __syncthreads();
    for (int off = 1; off < 512; off <<= 1) {
        int x = sd[t];
        int y = (t >= off) ? sd[t - off] : 0;
        __syncthreads();
        sd[t] = x + y;
        __syncthreads();
    }
    int excl = sd[t] - v;
    if (t <= NB) bucketOffs[t] = excl;  // bucketOffs[NB] = E sentinel
    if (t < NB) bucketCur[t] = excl;
}

// ---------------- phase 1c: partition edges into bucket runs ---------------
// Packs (dst&255)<<24 | src (src < 2^24). Per-block LDS count -> one global
// atomic per touched bucket -> contiguous run writes.
__global__ __launch_bounds__(256) void partition_kernel(
    const int* __restrict__ src, const int* __restrict__ dst, int E, int NB,
    int* __restrict__ bucketCur, unsigned int* __restrict__ bucketBuf) {
    __shared__ int cnt[NBMAX];
    __shared__ int base[NBMAX];
    int tid = threadIdx.x;
    for (int b = tid; b < NB; b += 256) cnt[b] = 0;
    __syncthreads();
    int eb = blockIdx.x * 4096;
    unsigned int pk[16];
    int bk[16], rk[16];
    for (int i = 0; i < 16; i++) {
        int e = eb + i * 256 + tid;
        if (e < E) {
            int d = dst[e];
            bk[i] = d >> 8;
            pk[i] = (unsigned)src[e] | ((unsigned)(d & 255) << 24);
            rk[i] = atomicAdd(&cnt[bk[i]], 1);
        } else {
            bk[i] = -1;
        }
    }
    __syncthreads();
    for (int b = tid; b < NB; b += 256)
        base[b] = cnt[b] ? atomicAdd(&bucketCur[b], cnt[b]) : 0;
    __syncthreads();
    for (int i = 0; i < 16; i++)
        if (bk[i] >= 0) bucketBuf[base[bk[i]] + rk[i]] = pk[i];
}

// ---------------- phase 2: per-bucket CSR build (deg/offs/sortedSrc) -------
// One block per bucket (256 nodes). All global writes dense.
__global__ __launch_bounds__(256) void csr_build(
    const unsigned int* __restrict__ bucketBuf, const int* __restrict__ bucketOffs,
    int N, int* __restrict__ deg, int* __restrict__ offs, int* __restrict__ sortedSrc) {
    __shared__ int h[256];
    __shared__ int sc[256];
    __shared__ int cur[256];
    int tid = threadIdx.x;
    int b = blockIdx.x;
    int n0 = b << 8;
    int bo = bucketOffs[b];
    int cnt = bucketOffs[b + 1] - bo;
    h[tid] = 0;
    __syncthreads();
    for (int i = tid; i < cnt; i += 256) atomicAdd(&h[bucketBuf[bo + i] >> 24], 1);
    __syncthreads();
    int v = h[tid];
    sc[tid] = v;
    __syncthreads();
    for (int off = 1; off < 256; off <<= 1) {
        int x = sc[tid];
        int y = (tid >= off) ? sc[tid - off] : 0;
        __syncthreads();
        sc[tid] = x + y;
        __syncthreads();
    }
    int excl = sc[tid] - v;
    cur[tid] = bo + excl;
    int n = n0 + tid;
    if (n < N) {
        deg[n] = v;
        offs[n] = bo + excl;
    }
    __syncthreads();
    for (int i = tid; i < cnt; i += 256) {
        unsigned int pv = bucketBuf[bo + i];
        int pos = atomicAdd(&cur[pv >> 24], 1);
        sortedSrc[pos] = (int)(pv & 0xFFFFFFu);
    }
}

// ---------------- f32 [N,128] -> packed bf16 u32 [N,64] ----------------
__global__ __launch_bounds__(256) void cvt_kernel(const float* __restrict__ in,
                                                  unsigned int* __restrict__ out, int n2) {
    int t = blockIdx.x * 256 + threadIdx.x;
    if (t < n2) {
        float2 v = ((const float2*)in)[t];
        out[t] = (unsigned)f2bf(v.x) | ((unsigned)f2bf(v.y) << 16);
    }
}

// ---------------- mean agg, bf16 source (wave/node, 8-deep pipeline) --------
__global__ __launch_bounds__(256) void agg_bf16_kernel(
    const unsigned int* __restrict__ srcFeats,
    const int* __restrict__ deg, const int* __restrict__ offs,
    const int* __restrict__ sortedSrc,
    unsigned int* __restrict__ dst, int Nn) {
    int wave = threadIdx.x >> 6, lane = threadIdx.x & 63;
    int n = blockIdx.x * 4 + wave;
    if (n >= Nn) return;
    int d = deg[n], st = offs[n];
    float a0 = 0.f, a1 = 0.f;
    int j = 0;
    for (; j + 8 <= d; j += 8) {
        int s[8];
#pragma unroll
        for (int u = 0; u < 8; u++) s[u] = sortedSrc[st + j + u];
        unsigned int uu[8];
#pragma unroll
        for (int u = 0; u < 8; u++) uu[u] = srcFeats[(size_t)s[u] * 64 + lane];
#pragma unroll
        for (int u = 0; u < 8; u++) {
            a0 += __uint_as_float(uu[u] << 16);
            a1 += __uint_as_float(uu[u] & 0xFFFF0000u);
        }
    }
    for (; j < d; j++) {
        int s = sortedSrc[st + j];
        unsigned int u = srcFeats[(size_t)s * 64 + lane];
        a0 += __uint_as_float(u << 16);
        a1 += __uint_as_float(u & 0xFFFF0000u);
    }
    float inv = 1.0f / (float)max(d, 1);
    dst[(size_t)n * 64 + lane] = (unsigned)f2bf(a0 * inv) | ((unsigned)f2bf(a1 * inv) << 16);
}

// ---------------- mean agg, f32 source (fallback layout B) ------------------
__global__ __launch_bounds__(256) void agg_f32_kernel(
    const float* __restrict__ srcFeats,
    const int* __restrict__ deg, const int* __restrict__ offs,
    const int* __restrict__ sortedSrc,
    unsigned int* __restrict__ dst, int Nn) {
    int wave = threadIdx.x >> 6, lane = threadIdx.x & 63;
    int n = blockIdx.x * 4 + wave;
    if (n >= Nn) return;
    int d = deg[n], st = offs[n];
    float a0 = 0.f, a1 = 0.f;
    int j = 0;
    for (; j + 4 <= d; j += 4) {
        int s[4];
#pragma unroll
        for (int u = 0; u < 4; u++) s[u] = sortedSrc[st + j + u];
        float2 v[4];
#pragma unroll
        for (int u = 0; u < 4; u++) v[u] = ((const float2*)(srcFeats + (size_t)s[u] * 128))[lane];
#pragma unroll
        for (int u = 0; u < 4; u++) {
            a0 += v[u].x;
            a1 += v[u].y;
        }
    }
    for (; j < d; j++) {
        int s = sortedSrc[st + j];
        float2 v = ((const float2*)(srcFeats + (size_t)s * 128))[lane];
        a0 += v.x;
        a1 += v.y;
    }
    float inv = 1.0f / (float)max(d, 1);
    dst[(size_t)n * 64 + lane] = (unsigned)f2bf(a0 * inv) | ((unsigned)f2bf(a1 * inv) << 16);
}

// ---------------- fused GEMM: out = act([Aagg|Aself] @ [Wn;Ws]^T + bn+bs) --
// Aagg: [N,128] bf16. Aself: bf16 (selfF32=0) or f32 (selfF32=1).
// Out: bf16 (outBf16=1) or f32. MFMA 16x16x32 bf16; 4 waves, 128 rows/block.
// Out may alias Aself (fallback layer 2): each wave reads only its own 32
// rows before writing them -> safe. (No __restrict__ on Aself/Out.)
__global__ __launch_bounds__(256) void gemm_kernel(
    const unsigned short* __restrict__ Aagg, const void* Aself,
    const float* __restrict__ Wn, const float* __restrict__ Ws,
    const float* __restrict__ bn, const float* __restrict__ bs,
    void* Out, int relu, int selfF32, int outBf16, int Nrows) {
    __shared__ unsigned short ldsB[8 * 8 * 64 * 8];  // 64 KB
    __shared__ float biasS[128];
    int tid = threadIdx.x;

    // frag(kt,nt,lane)[j] = B[kt*32+(lane>>4)*8+j][nt*16+(lane&15)]
    for (int i = 0; i < 16; i++) {
        int fi = tid + 256 * i;
        int kt = fi >> 9;
        int nt = (fi >> 6) & 7;
        int lane = fi & 63;
        int o = nt * 16 + (lane & 15);
        int k = kt * 32 + (lane >> 4) * 8;
        const float* srcp = (k < 128) ? (Wn + o * 128 + k) : (Ws + o * 128 + (k - 128));
        short8 v;
#pragma unroll
        for (int j = 0; j < 8; j++) v[j] = (short)f2bf(srcp[j]);
        *(short8*)(ldsB + (size_t)fi * 8) = v;
    }
    if (tid < 128) biasS[tid] = bn[tid] + bs[tid];
    __syncthreads();

    int wave = tid >> 6, lane = tid & 63;
    int quad = lane >> 4, mr = lane & 15;
    int rowBase = blockIdx.x * 128 + wave * 32;

    float4_ acc[2][8];
    float4_ z = {0.f, 0.f, 0.f, 0.f};
    for (int mt = 0; mt < 2; mt++)
        for (int nt = 0; nt < 8; nt++) acc[mt][nt] = z;

    for (int kt = 0; kt < 8; kt++) {
        int kk = (kt & 3) * 32 + quad * 8;
        short8 a[2];
        for (int mt = 0; mt < 2; mt++) {
            int row = rowBase + mt * 16 + mr;
            if (row >= Nrows) row = Nrows - 1;  // in-bounds; result discarded
            if (kt < 4) {
                a[mt] = *(const short8*)(Aagg + (size_t)row * 128 + kk);
            } else if (selfF32) {
                const float* p = (const float*)Aself + (size_t)row * 128 + kk;
                float4_ f0 = *(const float4_*)p;
                float4_ f1 = *(const float4_*)(p + 4);
                short8 t;
#pragma unroll
                for (int j = 0; j < 4; j++) {
                    t[j] = (short)f2bf(f0[j]);
                    t[4 + j] = (short)f2bf(f1[j]);
                }
                a[mt] = t;
            } else {
                a[mt] = *(const short8*)((const unsigned short*)Aself + (size_t)row * 128 + kk);
            }
        }
        for (int nt = 0; nt < 8; nt++) {
            short8 b = *(const short8*)(ldsB + ((size_t)(kt * 8 + nt) * 64 + lane) * 8);
            acc[0][nt] = __builtin_amdgcn_mfma_f32_16x16x32_bf16(a[0], b, acc[0][nt], 0, 0, 0);
            acc[1][nt] = __builtin_amdgcn_mfma_f32_16x16x32_bf16(a[1], b, acc[1][nt], 0, 0, 0);
        }
    }

    // C/D layout: col = lane&15, row = (lane>>4)*4 + reg
    for (int mt = 0; mt < 2; mt++) {
        for (int nt = 0; nt < 8; nt++) {
            int col = nt * 16 + mr;
            float bv = biasS[col];
            for (int r = 0; r < 4; r++) {
                int row = rowBase + mt * 16 + quad * 4 + r;
                if (row < Nrows) {
                    float v = acc[mt][nt][r] + bv;
                    if (relu) v = fmaxf(v, 0.f);
                    if (outBf16)
                        ((unsigned short*)Out)[(size_t)row * 128 + col] = f2bf(v);
                    else
                        ((float*)Out)[(size_t)row * 128 + col] = v;
                }
            }
        }
    }
}

extern "C" void kernel_launch(void* const* d_in, const int* in_sizes, int n_in,
                              void* d_out, int out_size, void* d_ws, size_t ws_size,
                              hipStream_t stream) {
    const float* x = (const float*)d_in[0];
    const int* ei = (const int*)d_in[1];
    const float* Wn1 = (const float*)d_in[2];
    const float* bn1 = (const float*)d_in[3];
    const float* Ws1 = (const float*)d_in[4];
    const float* bs1 = (const float*)d_in[5];
    const float* Wn2 = (const float*)d_in[6];
    const float* bn2 = (const float*)d_in[7];
    const float* Ws2 = (const float*)d_in[8];
    const float* bs2 = (const float*)d_in[9];

    const int N = in_sizes[0] / 128;
    const int E = in_sizes[1] / 2;
    const int* srcI = ei;
    const int* dstI = ei + E;
    const int NB = (N + 255) >> 8;  // <= NBMAX for N <= 131072

    char* ws = (char*)d_ws;
    size_t off = 0;
    auto alloc = [&](size_t bytes) -> void* {
        void* p = ws + off;
        off += (bytes + 255) & ~(size_t)255;
        return p;
    };
    int* deg = (int*)alloc((size_t)N * 4);
    int* offs = (int*)alloc((size_t)N * 4);
    int* bucketCnt = (int*)alloc((NBMAX + 1) * 4);
    int* bucketOffs = (int*)alloc((NBMAX + 1) * 4);
    int* bucketCur = (int*)alloc((NBMAX + 1) * 4);
    int* sortedSrc = (int*)alloc((size_t)E * 4);
    unsigned short* Aagg = (unsigned short*)alloc((size_t)N * 128 * 2);
    size_t baseNeed = off;
    size_t bf16Buf = ((size_t)N * 128 * 2 + 255) & ~(size_t)255;
    bool bigWs = (ws_size >= baseNeed + 2 * bf16Buf);
    unsigned int* xb = nullptr;
    unsigned short* h1b = nullptr;
    if (bigWs) {
        xb = (unsigned int*)alloc((size_t)N * 128 * 2);
        h1b = (unsigned short*)alloc((size_t)N * 128 * 2);
    }
    // bucketBuf (E u32, 6.4 MB) aliases Aagg (dead until agg1)
    unsigned int* bucketBuf = (unsigned int*)Aagg;

    // ---- CSR build (dense-write bucket partition) ----
    int ebBlocks = (E + 4095) / 4096;
    hipMemsetAsync(bucketCnt, 0, (size_t)NB * 4, stream);
    bucket_count<<<ebBlocks, 256, 0, stream>>>(dstI, E, NB, bucketCnt);
    bucket_scan<<<1, 512, 0, stream>>>(bucketCnt, NB, bucketOffs, bucketCur);
    partition_kernel<<<ebBlocks, 256, 0, stream>>>(srcI, dstI, E, NB, bucketCur, bucketBuf);
    csr_build<<<NB, 256, 0, stream>>>(bucketBuf, bucketOffs, N, deg, offs, sortedSrc);

    int aggBlocks = (N + 3) / 4;
    int gemmBlocks = (N + 127) / 128;

    if (bigWs) {
        // Layout A: all gathers bf16 (256 B/row)
        int n2 = N * 64;
        cvt_kernel<<<(n2 + 255) / 256, 256, 0, stream>>>(x, xb, n2);
        agg_bf16_kernel<<<aggBlocks, 256, 0, stream>>>(xb, deg, offs, sortedSrc,
                                                       (unsigned int*)Aagg, N);
        gemm_kernel<<<gemmBlocks, 256, 0, stream>>>(Aagg, xb, Wn1, Ws1, bn1, bs1, h1b,
                                                    1, 0, 1, N);
        agg_bf16_kernel<<<aggBlocks, 256, 0, stream>>>((const unsigned int*)h1b, deg, offs,
                                                       sortedSrc, (unsigned int*)Aagg, N);
        gemm_kernel<<<gemmBlocks, 256, 0, stream>>>(Aagg, h1b, Wn2, Ws2, bn2, bs2, d_out,
                                                    0, 0, 0, N);
    } else {
        // Layout B: f32 gathers, h1 f32 staged in d_out
        float* h1 = (float*)d_out;
        agg_f32_kernel<<<aggBlocks, 256, 0, stream>>>(x, deg, offs, sortedSrc,
                                                      (unsigned int*)Aagg, N);
        gemm_kernel<<<gemmBlocks, 256, 0, stream>>>(Aagg, x, Wn1, Ws1, bn1, bs1, h1,
                                                    1, 1, 0, N);
        agg_f32_kernel<<<aggBlocks, 256, 0, stream>>>(h1, deg, offs, sortedSrc,
                                                      (unsigned int*)Aagg, N);
        gemm_kernel<<<gemmBlocks, 256, 0, stream>>>(Aagg, h1, Wn2, Ws2, bn2, bs2, d_out,
                                                    0, 1, 0, N);
    }
}

// Round 7
// 358.246 us; speedup vs baseline: 1.9775x; 1.0707x over previous
//
#include <hip/hip_runtime.h>
#include <hip/hip_bf16.h>

// GraphSAGE 2-layer, N=100000, E=1.6M, D=128. f32 I/O, bf16 MFMA compute.
//
// R7: (1) wprep pre-converts+pre-swizzles combined weights to bf16 fragment
//     order once per launch -> gemm LDS B-fill is a pure 16B/lane copy (no
//     f32 reads, no per-block cvt). (2) agg gather loop unrolled to 16
//     (avg degree) for 16 outstanding 256B gathers per wave.
//
// Pipeline: memset bucketCnt -> bucket_count -> bucket_scan -> partition ->
//   csr_build -> wprep -> cvt(x->bf16) -> agg1 -> gemm1(relu->h1b bf16) ->
//   agg2 -> gemm2 -> d_out f32.  Fallback layout B (small ws): f32 gathers,
//   h1 f32 staged in d_out.

typedef __attribute__((ext_vector_type(8))) short short8;
typedef __attribute__((ext_vector_type(4))) float float4_;

#define NBMAX 512  // max buckets (256 nodes each) -> N <= 131072

__device__ __forceinline__ unsigned short f2bf(float f) {
    unsigned int u = __float_as_uint(f);
    unsigned int r = (u + 0x7FFFu + ((u >> 16) & 1u)) >> 16;
    return (unsigned short)r;
}

// ---------------- phase 1a: bucket histogram (bucket = dst >> 8) -----------
__global__ __launch_bounds__(256) void bucket_count(const int* __restrict__ dst, int E, int NB,
                                                    int* __restrict__ bucketCnt) {
    __shared__ int h[NBMAX];
    int tid = threadIdx.x;
    for (int b = tid; b < NB; b += 256) h[b] = 0;
    __syncthreads();
    int base = blockIdx.x * 4096;
    for (int i = 0; i < 16; i++) {
        int e = base + i * 256 + tid;
        if (e < E) atomicAdd(&h[dst[e] >> 8], 1);
    }
    __syncthreads();
    for (int b = tid; b < NB; b += 256)
        if (h[b]) atomicAdd(&bucketCnt[b], h[b]);
}

// ---------------- phase 1b: scan bucket counts (1 block) -------------------
__global__ __launch_bounds__(512) void bucket_scan(const int* __restrict__ bucketCnt, int NB,
                                                   int* __restrict__ bucketOffs,
                                                   int* __restrict__ bucketCur) {
    __shared__ int sd[512];
    int t = threadIdx.x;
    int v = (t < NB) ? bucketCnt[t] : 0;
    sd[t] = v;
    __syncthreads();
    for (int off = 1; off < 512; off <<= 1) {
        int x = sd[t];
        int y = (t >= off) ? sd[t - off] : 0;
        __syncthreads();
        sd[t] = x + y;
        __syncthreads();
    }
    int excl = sd[t] - v;
    if (t <= NB) bucketOffs[t] = excl;  // bucketOffs[NB] = E sentinel
    if (t < NB) bucketCur[t] = excl;
}

// ---------------- phase 1c: partition edges into bucket runs ---------------
__global__ __launch_bounds__(256) void partition_kernel(
    const int* __restrict__ src, const int* __restrict__ dst, int E, int NB,
    int* __restrict__ bucketCur, unsigned int* __restrict__ bucketBuf) {
    __shared__ int cnt[NBMAX];
    __shared__ int base[NBMAX];
    int tid = threadIdx.x;
    for (int b = tid; b < NB; b += 256) cnt[b] = 0;
    __syncthreads();
    int eb = blockIdx.x * 4096;
    unsigned int pk[16];
    int bk[16], rk[16];
    for (int i = 0; i < 16; i++) {
        int e = eb + i * 256 + tid;
        if (e < E) {
            int d = dst[e];
            bk[i] = d >> 8;
            pk[i] = (unsigned)src[e] | ((unsigned)(d & 255) << 24);
            rk[i] = atomicAdd(&cnt[bk[i]], 1);
        } else {
            bk[i] = -1;
        }
    }
    __syncthreads();
    for (int b = tid; b < NB; b += 256)
        base[b] = cnt[b] ? atomicAdd(&bucketCur[b], cnt[b]) : 0;
    __syncthreads();
    for (int i = 0; i < 16; i++)
        if (bk[i] >= 0) bucketBuf[base[bk[i]] + rk[i]] = pk[i];
}

// ---------------- phase 2: per-bucket CSR build ----------------------------
__global__ __launch_bounds__(256) void csr_build(
    const unsigned int* __restrict__ bucketBuf, const int* __restrict__ bucketOffs,
    int N, int* __restrict__ deg, int* __restrict__ offs, int* __restrict__ sortedSrc) {
    __shared__ int h[256];
    __shared__ int sc[256];
    __shared__ int cur[256];
    int tid = threadIdx.x;
    int b = blockIdx.x;
    int n0 = b << 8;
    int bo = bucketOffs[b];
    int cnt = bucketOffs[b + 1] - bo;
    h[tid] = 0;
    __syncthreads();
    for (int i = tid; i < cnt; i += 256) atomicAdd(&h[bucketBuf[bo + i] >> 24], 1);
    __syncthreads();
    int v = h[tid];
    sc[tid] = v;
    __syncthreads();
    for (int off = 1; off < 256; off <<= 1) {
        int x = sc[tid];
        int y = (tid >= off) ? sc[tid - off] : 0;
        __syncthreads();
        sc[tid] = x + y;
        __syncthreads();
    }
    int excl = sc[tid] - v;
    cur[tid] = bo + excl;
    int n = n0 + tid;
    if (n < N) {
        deg[n] = v;
        offs[n] = bo + excl;
    }
    __syncthreads();
    for (int i = tid; i < cnt; i += 256) {
        unsigned int pv = bucketBuf[bo + i];
        int pos = atomicAdd(&cur[pv >> 24], 1);
        sortedSrc[pos] = (int)(pv & 0xFFFFFFu);
    }
}

// ---------------- weight prep: f32 W -> bf16 pre-swizzled fragments --------
// Grid: 32 blocks. Layer l = b>>4; frag fi = (b&15)*256 + tid in [0,4096).
// Bpre[l] frag(kt,nt,lane)[j] = B[kt*32+(lane>>4)*8+j][nt*16+(lane&15)],
// B[k][o] = k<128 ? Wn[o][k] : Ws[o][k-128]. biasPre[l][o] = bn[o]+bs[o].
__global__ __launch_bounds__(256) void wprep_kernel(
    const float* __restrict__ Wn1, const float* __restrict__ Ws1,
    const float* __restrict__ bn1, const float* __restrict__ bs1,
    const float* __restrict__ Wn2, const float* __restrict__ Ws2,
    const float* __restrict__ bn2, const float* __restrict__ bs2,
    unsigned short* __restrict__ Bpre, float* __restrict__ biasPre) {
    int b = blockIdx.x, tid = threadIdx.x;
    int l = b >> 4;
    const float* Wn = l ? Wn2 : Wn1;
    const float* Ws = l ? Ws2 : Ws1;
    int fi = (b & 15) * 256 + tid;
    int kt = fi >> 9;
    int nt = (fi >> 6) & 7;
    int lane = fi & 63;
    int o = nt * 16 + (lane & 15);
    int k = kt * 32 + (lane >> 4) * 8;
    const float* srcp = (k < 128) ? (Wn + o * 128 + k) : (Ws + o * 128 + (k - 128));
    short8 v;
#pragma unroll
    for (int j = 0; j < 8; j++) v[j] = (short)f2bf(srcp[j]);
    ((short8*)(Bpre + (size_t)l * 32768))[fi] = v;
    if ((b & 15) == 0 && tid < 128) {
        const float* bn = l ? bn2 : bn1;
        const float* bs = l ? bs2 : bs1;
        biasPre[l * 128 + tid] = bn[tid] + bs[tid];
    }
}

// ---------------- f32 [N,128] -> packed bf16 u32 [N,64] ----------------
__global__ __launch_bounds__(256) void cvt_kernel(const float* __restrict__ in,
                                                  unsigned int* __restrict__ out, int n2) {
    int t = blockIdx.x * 256 + threadIdx.x;
    if (t < n2) {
        float2 v = ((const float2*)in)[t];
        out[t] = (unsigned)f2bf(v.x) | ((unsigned)f2bf(v.y) << 16);
    }
}

// ---------------- mean agg, bf16 source (wave/node, 16-deep pipeline) -------
__global__ __launch_bounds__(256) void agg_bf16_kernel(
    const unsigned int* __restrict__ srcFeats,
    const int* __restrict__ deg, const int* __restrict__ offs,
    const int* __restrict__ sortedSrc,
    unsigned int* __restrict__ dst, int Nn) {
    int wave = threadIdx.x >> 6, lane = threadIdx.x & 63;
    int n = blockIdx.x * 4 + wave;
    if (n >= Nn) return;
    int d = deg[n], st = offs[n];
    float a0 = 0.f, a1 = 0.f;
    int j = 0;
    for (; j + 16 <= d; j += 16) {
        int s[16];
#pragma unroll
        for (int u = 0; u < 16; u++) s[u] = sortedSrc[st + j + u];
        unsigned int uu[16];
#pragma unroll
        for (int u = 0; u < 16; u++) uu[u] = srcFeats[(size_t)s[u] * 64 + lane];
#pragma unroll
        for (int u = 0; u < 16; u++) {
            a0 += __uint_as_float(uu[u] << 16);
            a1 += __uint_as_float(uu[u] & 0xFFFF0000u);
        }
    }
    for (; j + 8 <= d; j += 8) {
        int s[8];
#pragma unroll
        for (int u = 0; u < 8; u++) s[u] = sortedSrc[st + j + u];
        unsigned int uu[8];
#pragma unroll
        for (int u = 0; u < 8; u++) uu[u] = srcFeats[(size_t)s[u] * 64 + lane];
#pragma unroll
        for (int u = 0; u < 8; u++) {
            a0 += __uint_as_float(uu[u] << 16);
            a1 += __uint_as_float(uu[u] & 0xFFFF0000u);
        }
    }
    for (; j < d; j++) {
        int s = sortedSrc[st + j];
        unsigned int u = srcFeats[(size_t)s * 64 + lane];
        a0 += __uint_as_float(u << 16);
        a1 += __uint_as_float(u & 0xFFFF0000u);
    }
    float inv = 1.0f / (float)max(d, 1);
    dst[(size_t)n * 64 + lane] = (unsigned)f2bf(a0 * inv) | ((unsigned)f2bf(a1 * inv) << 16);
}

// ---------------- mean agg, f32 source (fallback layout B) ------------------
__global__ __launch_bounds__(256) void agg_f32_kernel(
    const float* __restrict__ srcFeats,
    const int* __restrict__ deg, const int* __restrict__ offs,
    const int* __restrict__ sortedSrc,
    unsigned int* __restrict__ dst, int Nn) {
    int wave = threadIdx.x >> 6, lane = threadIdx.x & 63;
    int n = blockIdx.x * 4 + wave;
    if (n >= Nn) return;
    int d = deg[n], st = offs[n];
    float a0 = 0.f, a1 = 0.f;
    int j = 0;
    for (; j + 4 <= d; j += 4) {
        int s[4];
#pragma unroll
        for (int u = 0; u < 4; u++) s[u] = sortedSrc[st + j + u];
        float2 v[4];
#pragma unroll
        for (int u = 0; u < 4; u++) v[u] = ((const float2*)(srcFeats + (size_t)s[u] * 128))[lane];
#pragma unroll
        for (int u = 0; u < 4; u++) {
            a0 += v[u].x;
            a1 += v[u].y;
        }
    }
    for (; j < d; j++) {
        int s = sortedSrc[st + j];
        float2 v = ((const float2*)(srcFeats + (size_t)s * 128))[lane];
        a0 += v.x;
        a1 += v.y;
    }
    float inv = 1.0f / (float)max(d, 1);
    dst[(size_t)n * 64 + lane] = (unsigned)f2bf(a0 * inv) | ((unsigned)f2bf(a1 * inv) << 16);
}

// ---------------- fused GEMM: out = act([Aagg|Aself] @ B^T + bias) ---------
// Aagg: [N,128] bf16. Aself: bf16 (selfF32=0) or f32 (selfF32=1).
// Bpre: 64KB pre-swizzled bf16 fragments; biasPre: 128 f32 (bn+bs).
// Out: bf16 (outBf16=1) or f32. MFMA 16x16x32 bf16; 4 waves, 128 rows/block.
// Out may alias Aself (fallback layer 2): each wave reads only its own 32
// rows before writing them -> safe. (No __restrict__ on Aself/Out.)
__global__ __launch_bounds__(256) void gemm_kernel(
    const unsigned short* __restrict__ Aagg, const void* Aself,
    const unsigned short* __restrict__ Bpre, const float* __restrict__ biasPre,
    void* Out, int relu, int selfF32, int outBf16, int Nrows) {
    __shared__ unsigned short ldsB[8 * 8 * 64 * 8];  // 64 KB
    __shared__ float biasS[128];
    int tid = threadIdx.x;

    // Pure coalesced copy: Bpre is already bf16 in fragment order.
#pragma unroll
    for (int i = 0; i < 16; i++) {
        int fi = tid + 256 * i;
        ((short8*)ldsB)[fi] = ((const short8*)Bpre)[fi];
    }
    if (tid < 128) biasS[tid] = biasPre[tid];
    __syncthreads();

    int wave = tid >> 6, lane = tid & 63;
    int quad = lane >> 4, mr = lane & 15;
    int rowBase = blockIdx.x * 128 + wave * 32;

    float4_ acc[2][8];
    float4_ z = {0.f, 0.f, 0.f, 0.f};
    for (int mt = 0; mt < 2; mt++)
        for (int nt = 0; nt < 8; nt++) acc[mt][nt] = z;

    for (int kt = 0; kt < 8; kt++) {
        int kk = (kt & 3) * 32 + quad * 8;
        short8 a[2];
        for (int mt = 0; mt < 2; mt++) {
            int row = rowBase + mt * 16 + mr;
            if (row >= Nrows) row = Nrows - 1;  // in-bounds; result discarded
            if (kt < 4) {
                a[mt] = *(const short8*)(Aagg + (size_t)row * 128 + kk);
            } else if (selfF32) {
                const float* p = (const float*)Aself + (size_t)row * 128 + kk;
                float4_ f0 = *(const float4_*)p;
                float4_ f1 = *(const float4_*)(p + 4);
                short8 t;
#pragma unroll
                for (int j = 0; j < 4; j++) {
                    t[j] = (short)f2bf(f0[j]);
                    t[4 + j] = (short)f2bf(f1[j]);
                }
                a[mt] = t;
            } else {
                a[mt] = *(const short8*)((const unsigned short*)Aself + (size_t)row * 128 + kk);
            }
        }
        for (int nt = 0; nt < 8; nt++) {
            short8 b = *(const short8*)(ldsB + ((size_t)(kt * 8 + nt) * 64 + lane) * 8);
            acc[0][nt] = __builtin_amdgcn_mfma_f32_16x16x32_bf16(a[0], b, acc[0][nt], 0, 0, 0);
            acc[1][nt] = __builtin_amdgcn_mfma_f32_16x16x32_bf16(a[1], b, acc[1][nt], 0, 0, 0);
        }
    }

    // C/D layout: col = lane&15, row = (lane>>4)*4 + reg
    for (int mt = 0; mt < 2; mt++) {
        for (int nt = 0; nt < 8; nt++) {
            int col = nt * 16 + mr;
            float bv = biasS[col];
            for (int r = 0; r < 4; r++) {
                int row = rowBase + mt * 16 + quad * 4 + r;
                if (row < Nrows) {
                    float v = acc[mt][nt][r] + bv;
                    if (relu) v = fmaxf(v, 0.f);
                    if (outBf16)
                        ((unsigned short*)Out)[(size_t)row * 128 + col] = f2bf(v);
                    else
                        ((float*)Out)[(size_t)row * 128 + col] = v;
                }
            }
        }
    }
}

extern "C" void kernel_launch(void* const* d_in, const int* in_sizes, int n_in,
                              void* d_out, int out_size, void* d_ws, size_t ws_size,
                              hipStream_t stream) {
    const float* x = (const float*)d_in[0];
    const int* ei = (const int*)d_in[1];
    const float* Wn1 = (const float*)d_in[2];
    const float* bn1 = (const float*)d_in[3];
    const float* Ws1 = (const float*)d_in[4];
    const float* bs1 = (const float*)d_in[5];
    const float* Wn2 = (const float*)d_in[6];
    const float* bn2 = (const float*)d_in[7];
    const float* Ws2 = (const float*)d_in[8];
    const float* bs2 = (const float*)d_in[9];

    const int N = in_sizes[0] / 128;
    const int E = in_sizes[1] / 2;
    const int* srcI = ei;
    const int* dstI = ei + E;
    const int NB = (N + 255) >> 8;  // <= NBMAX for N <= 131072

    char* ws = (char*)d_ws;
    size_t off = 0;
    auto alloc = [&](size_t bytes) -> void* {
        void* p = ws + off;
        off += (bytes + 255) & ~(size_t)255;
        return p;
    };
    int* deg = (int*)alloc((size_t)N * 4);
    int* offs = (int*)alloc((size_t)N * 4);
    int* bucketCnt = (int*)alloc((NBMAX + 1) * 4);
    int* bucketOffs = (int*)alloc((NBMAX + 1) * 4);
    int* bucketCur = (int*)alloc((NBMAX + 1) * 4);
    unsigned short* Bpre = (unsigned short*)alloc(2 * 32768 * 2);
    float* biasPre = (float*)alloc(2 * 128 * 4);
    int* sortedSrc = (int*)alloc((size_t)E * 4);
    unsigned short* Aagg = (unsigned short*)alloc((size_t)N * 128 * 2);
    size_t baseNeed = off;
    size_t bf16Buf = ((size_t)N * 128 * 2 + 255) & ~(size_t)255;
    bool bigWs = (ws_size >= baseNeed + 2 * bf16Buf);
    unsigned int* xb = nullptr;
    unsigned short* h1b = nullptr;
    if (bigWs) {
        xb = (unsigned int*)alloc((size_t)N * 128 * 2);
        h1b = (unsigned short*)alloc((size_t)N * 128 * 2);
    }
    // bucketBuf (E u32, 6.4 MB) aliases Aagg (dead until agg1)
    unsigned int* bucketBuf = (unsigned int*)Aagg;

    // ---- CSR build (dense-write bucket partition) ----
    int ebBlocks = (E + 4095) / 4096;
    hipMemsetAsync(bucketCnt, 0, (size_t)NB * 4, stream);
    bucket_count<<<ebBlocks, 256, 0, stream>>>(dstI, E, NB, bucketCnt);
    bucket_scan<<<1, 512, 0, stream>>>(bucketCnt, NB, bucketOffs, bucketCur);
    partition_kernel<<<ebBlocks, 256, 0, stream>>>(srcI, dstI, E, NB, bucketCur, bucketBuf);
    csr_build<<<NB, 256, 0, stream>>>(bucketBuf, bucketOffs, N, deg, offs, sortedSrc);

    // ---- weight prep (both layers) ----
    wprep_kernel<<<32, 256, 0, stream>>>(Wn1, Ws1, bn1, bs1, Wn2, Ws2, bn2, bs2, Bpre, biasPre);

    int aggBlocks = (N + 3) / 4;
    int gemmBlocks = (N + 127) / 128;

    if (bigWs) {
        // Layout A: all gathers bf16 (256 B/row)
        int n2 = N * 64;
        cvt_kernel<<<(n2 + 255) / 256, 256, 0, stream>>>(x, xb, n2);
        agg_bf16_kernel<<<aggBlocks, 256, 0, stream>>>(xb, deg, offs, sortedSrc,
                                                       (unsigned int*)Aagg, N);
        gemm_kernel<<<gemmBlocks, 256, 0, stream>>>(Aagg, xb, Bpre, biasPre, h1b, 1, 0, 1, N);
        agg_bf16_kernel<<<aggBlocks, 256, 0, stream>>>((const unsigned int*)h1b, deg, offs,
                                                       sortedSrc, (unsigned int*)Aagg, N);
        gemm_kernel<<<gemmBlocks, 256, 0, stream>>>(Aagg, h1b, Bpre + 32768, biasPre + 128,
                                                    d_out, 0, 0, 0, N);
    } else {
        // Layout B: f32 gathers, h1 f32 staged in d_out
        float* h1 = (float*)d_out;
        agg_f32_kernel<<<aggBlocks, 256, 0, stream>>>(x, deg, offs, sortedSrc,
                                                      (unsigned int*)Aagg, N);
        gemm_kernel<<<gemmBlocks, 256, 0, stream>>>(Aagg, x, Bpre, biasPre, h1, 1, 1, 0, N);
        agg_f32_kernel<<<aggBlocks, 256, 0, stream>>>(h1, deg, offs, sortedSrc,
                                                      (unsigned int*)Aagg, N);
        gemm_kernel<<<gemmBlocks, 256, 0, stream>>>(Aagg, h1, Bpre + 32768, biasPre + 128,
                                                    d_out, 0, 1, 0, N);
    }
}

// Round 8
// 356.251 us; speedup vs baseline: 1.9886x; 1.0056x over previous
//
#include <hip/hip_runtime.h>
#include <hip/hip_bf16.h>

// GraphSAGE 2-layer, N=100000, E=1.6M, D=128. f32 I/O, bf16 MFMA compute.
//
// R8: dispatch-count reduction (13 -> 9) + overlap of independent work:
//   - wprep fused into partition's grid tail (blocks >= ebBlocks).
//   - cvt (x->bf16) fused into csr_build's grid tail (blocks >= NB).
//   - agg gathers use readfirstlane'd SGPR row bases (less VALU addr math).
// agg is at its structural plateau: time ~= FETCH(179MB) / ~3TB/s L2-miss
// path; table (25.6MB) >> per-XCD L2 (4MB), random srcs -> no locality.
//
// Pipeline (9 dispatches): memset bucketCnt -> bucket_count -> bucket_scan ->
//   partition+wprep -> csr_build+cvt -> agg1 -> gemm1(relu->h1b) -> agg2 ->
//   gemm2 -> d_out f32.  Fallback layout B (small ws): f32 gathers, h1 f32
//   staged in d_out.

typedef __attribute__((ext_vector_type(8))) short short8;
typedef __attribute__((ext_vector_type(4))) float float4_;

#define NBMAX 512  // max buckets (256 nodes each) -> N <= 131072

__device__ __forceinline__ unsigned short f2bf(float f) {
    unsigned int u = __float_as_uint(f);
    unsigned int r = (u + 0x7FFFu + ((u >> 16) & 1u)) >> 16;
    return (unsigned short)r;
}

// ---------------- phase 1a: bucket histogram (bucket = dst >> 8) -----------
__global__ __launch_bounds__(256) void bucket_count(const int* __restrict__ dst, int E, int NB,
                                                    int* __restrict__ bucketCnt) {
    __shared__ int h[NBMAX];
    int tid = threadIdx.x;
    for (int b = tid; b < NB; b += 256) h[b] = 0;
    __syncthreads();
    int base = blockIdx.x * 4096;
    for (int i = 0; i < 16; i++) {
        int e = base + i * 256 + tid;
        if (e < E) atomicAdd(&h[dst[e] >> 8], 1);
    }
    __syncthreads();
    for (int b = tid; b < NB; b += 256)
        if (h[b]) atomicAdd(&bucketCnt[b], h[b]);
}

// ---------------- phase 1b: scan bucket counts (1 block) -------------------
__global__ __launch_bounds__(512) void bucket_scan(const int* __restrict__ bucketCnt, int NB,
                                                   int* __restrict__ bucketOffs,
                                                   int* __restrict__ bucketCur) {
    __shared__ int sd[512];
    int t = threadIdx.x;
    int v = (t < NB) ? bucketCnt[t] : 0;
    sd[t] = v;
    __syncthreads();
    for (int off = 1; off < 512; off <<= 1) {
        int x = sd[t];
        int y = (t >= off) ? sd[t - off] : 0;
        __syncthreads();
        sd[t] = x + y;
        __syncthreads();
    }
    int excl = sd[t] - v;
    if (t <= NB) bucketOffs[t] = excl;  // bucketOffs[NB] = E sentinel
    if (t < NB) bucketCur[t] = excl;
}

// ---------------- phase 1c: partition edges + (tail blocks) weight prep ----
__global__ __launch_bounds__(256) void partition_wprep(
    const int* __restrict__ src, const int* __restrict__ dst, int E, int NB, int partBlocks,
    int* __restrict__ bucketCur, unsigned int* __restrict__ bucketBuf,
    const float* __restrict__ Wn1, const float* __restrict__ Ws1,
    const float* __restrict__ bn1, const float* __restrict__ bs1,
    const float* __restrict__ Wn2, const float* __restrict__ Ws2,
    const float* __restrict__ bn2, const float* __restrict__ bs2,
    unsigned short* __restrict__ Bpre, float* __restrict__ biasPre) {
    int tid = threadIdx.x;
    if ((int)blockIdx.x >= partBlocks) {
        // ---- weight prep: f32 W -> bf16 pre-swizzled fragments ----
        int wb = blockIdx.x - partBlocks;  // [0,32)
        int l = wb >> 4;
        const float* Wn = l ? Wn2 : Wn1;
        const float* Ws = l ? Ws2 : Ws1;
        int fi = (wb & 15) * 256 + tid;
        int kt = fi >> 9;
        int nt = (fi >> 6) & 7;
        int lane = fi & 63;
        int o = nt * 16 + (lane & 15);
        int k = kt * 32 + (lane >> 4) * 8;
        const float* srcp = (k < 128) ? (Wn + o * 128 + k) : (Ws + o * 128 + (k - 128));
        short8 v;
#pragma unroll
        for (int j = 0; j < 8; j++) v[j] = (short)f2bf(srcp[j]);
        ((short8*)(Bpre + (size_t)l * 32768))[fi] = v;
        if ((wb & 15) == 0 && tid < 128) {
            const float* bn = l ? bn2 : bn1;
            const float* bs = l ? bs2 : bs1;
            biasPre[l * 128 + tid] = bn[tid] + bs[tid];
        }
        return;
    }
    __shared__ int cnt[NBMAX];
    __shared__ int base[NBMAX];
    for (int b = tid; b < NB; b += 256) cnt[b] = 0;
    __syncthreads();
    int eb = blockIdx.x * 4096;
    unsigned int pk[16];
    int bk[16], rk[16];
    for (int i = 0; i < 16; i++) {
        int e = eb + i * 256 + tid;
        if (e < E) {
            int d = dst[e];
            bk[i] = d >> 8;
            pk[i] = (unsigned)src[e] | ((unsigned)(d & 255) << 24);
            rk[i] = atomicAdd(&cnt[bk[i]], 1);
        } else {
            bk[i] = -1;
        }
    }
    __syncthreads();
    for (int b = tid; b < NB; b += 256)
        base[b] = cnt[b] ? atomicAdd(&bucketCur[b], cnt[b]) : 0;
    __syncthreads();
    for (int i = 0; i < 16; i++)
        if (bk[i] >= 0) bucketBuf[base[bk[i]] + rk[i]] = pk[i];
}

// ---------------- phase 2: per-bucket CSR build + (tail blocks) x->bf16 ----
__global__ __launch_bounds__(256) void csrbuild_cvt(
    const unsigned int* __restrict__ bucketBuf, const int* __restrict__ bucketOffs,
    int N, int NB, int* __restrict__ deg, int* __restrict__ offs, int* __restrict__ sortedSrc,
    const float* __restrict__ xin, unsigned int* __restrict__ xb, int n2) {
    int tid = threadIdx.x;
    if ((int)blockIdx.x >= NB) {
        // ---- cvt: f32 [N,128] -> packed bf16 u32 [N,64], 8 u32/thread ----
        int cb = blockIdx.x - NB;
        int base = cb * 2048 + tid;
        if (xb) {
#pragma unroll
            for (int i = 0; i < 8; i++) {
                int t = base + i * 256;
                if (t < n2) {
                    float2 v = ((const float2*)xin)[t];
                    xb[t] = (unsigned)f2bf(v.x) | ((unsigned)f2bf(v.y) << 16);
                }
            }
        }
        return;
    }
    __shared__ int h[256];
    __shared__ int sc[256];
    __shared__ int cur[256];
    int b = blockIdx.x;
    int n0 = b << 8;
    int bo = bucketOffs[b];
    int cnt = bucketOffs[b + 1] - bo;
    h[tid] = 0;
    __syncthreads();
    for (int i = tid; i < cnt; i += 256) atomicAdd(&h[bucketBuf[bo + i] >> 24], 1);
    __syncthreads();
    int v = h[tid];
    sc[tid] = v;
    __syncthreads();
    for (int off = 1; off < 256; off <<= 1) {
        int x = sc[tid];
        int y = (tid >= off) ? sc[tid - off] : 0;
        __syncthreads();
        sc[tid] = x + y;
        __syncthreads();
    }
    int excl = sc[tid] - v;
    cur[tid] = bo + excl;
    int n = n0 + tid;
    if (n < N) {
        deg[n] = v;
        offs[n] = bo + excl;
    }
    __syncthreads();
    for (int i = tid; i < cnt; i += 256) {
        unsigned int pv = bucketBuf[bo + i];
        int pos = atomicAdd(&cur[pv >> 24], 1);
        sortedSrc[pos] = (int)(pv & 0xFFFFFFu);
    }
}

// ---------------- mean agg, bf16 source (wave/node, 16-deep, SGPR bases) ----
__global__ __launch_bounds__(256) void agg_bf16_kernel(
    const unsigned int* __restrict__ srcFeats,
    const int* __restrict__ deg, const int* __restrict__ offs,
    const int* __restrict__ sortedSrc,
    unsigned int* __restrict__ dst, int Nn) {
    int wave = threadIdx.x >> 6, lane = threadIdx.x & 63;
    int n = blockIdx.x * 4 + wave;
    if (n >= Nn) return;
    int d = deg[n], st = offs[n];
    float a0 = 0.f, a1 = 0.f;
    int j = 0;
    for (; j + 16 <= d; j += 16) {
        unsigned int uu[16];
#pragma unroll
        for (int u = 0; u < 16; u++) {
            int s = __builtin_amdgcn_readfirstlane(sortedSrc[st + j + u]);
            uu[u] = (srcFeats + (size_t)s * 64)[lane];
        }
#pragma unroll
        for (int u = 0; u < 16; u++) {
            a0 += __uint_as_float(uu[u] << 16);
            a1 += __uint_as_float(uu[u] & 0xFFFF0000u);
        }
    }
    for (; j + 8 <= d; j += 8) {
        unsigned int uu[8];
#pragma unroll
        for (int u = 0; u < 8; u++) {
            int s = __builtin_amdgcn_readfirstlane(sortedSrc[st + j + u]);
            uu[u] = (srcFeats + (size_t)s * 64)[lane];
        }
#pragma unroll
        for (int u = 0; u < 8; u++) {
            a0 += __uint_as_float(uu[u] << 16);
            a1 += __uint_as_float(uu[u] & 0xFFFF0000u);
        }
    }
    for (; j < d; j++) {
        int s = __builtin_amdgcn_readfirstlane(sortedSrc[st + j]);
        unsigned int u = (srcFeats + (size_t)s * 64)[lane];
        a0 += __uint_as_float(u << 16);
        a1 += __uint_as_float(u & 0xFFFF0000u);
    }
    float inv = 1.0f / (float)max(d, 1);
    dst[(size_t)n * 64 + lane] = (unsigned)f2bf(a0 * inv) | ((unsigned)f2bf(a1 * inv) << 16);
}

// ---------------- mean agg, f32 source (fallback layout B) ------------------
__global__ __launch_bounds__(256) void agg_f32_kernel(
    const float* __restrict__ srcFeats,
    const int* __restrict__ deg, const int* __restrict__ offs,
    const int* __restrict__ sortedSrc,
    unsigned int* __restrict__ dst, int Nn) {
    int wave = threadIdx.x >> 6, lane = threadIdx.x & 63;
    int n = blockIdx.x * 4 + wave;
    if (n >= Nn) return;
    int d = deg[n], st = offs[n];
    float a0 = 0.f, a1 = 0.f;
    int j = 0;
    for (; j + 8 <= d; j += 8) {
        float2 v[8];
#pragma unroll
        for (int u = 0; u < 8; u++) {
            int s = __builtin_amdgcn_readfirstlane(sortedSrc[st + j + u]);
            v[u] = ((const float2*)(srcFeats + (size_t)s * 128))[lane];
        }
#pragma unroll
        for (int u = 0; u < 8; u++) {
            a0 += v[u].x;
            a1 += v[u].y;
        }
    }
    for (; j < d; j++) {
        int s = __builtin_amdgcn_readfirstlane(sortedSrc[st + j]);
        float2 v = ((const float2*)(srcFeats + (size_t)s * 128))[lane];
        a0 += v.x;
        a1 += v.y;
    }
    float inv = 1.0f / (float)max(d, 1);
    dst[(size_t)n * 64 + lane] = (unsigned)f2bf(a0 * inv) | ((unsigned)f2bf(a1 * inv) << 16);
}

// ---------------- fused GEMM: out = act([Aagg|Aself] @ B^T + bias) ---------
// Aagg: [N,128] bf16. Aself: bf16 (selfF32=0) or f32 (selfF32=1).
// Bpre: 64KB pre-swizzled bf16 fragments; biasPre: 128 f32 (bn+bs).
// Out: bf16 (outBf16=1) or f32. MFMA 16x16x32 bf16; 4 waves, 128 rows/block.
// Out may alias Aself (fallback layer 2): each wave reads only its own 32
// rows before writing them -> safe. (No __restrict__ on Aself/Out.)
__global__ __launch_bounds__(256) void gemm_kernel(
    const unsigned short* __restrict__ Aagg, const void* Aself,
    const unsigned short* __restrict__ Bpre, const float* __restrict__ biasPre,
    void* Out, int relu, int selfF32, int outBf16, int Nrows) {
    __shared__ unsigned short ldsB[8 * 8 * 64 * 8];  // 64 KB
    __shared__ float biasS[128];
    int tid = threadIdx.x;

    // Pure coalesced copy: Bpre is already bf16 in fragment order.
#pragma unroll
    for (int i = 0; i < 16; i++) {
        int fi = tid + 256 * i;
        ((short8*)ldsB)[fi] = ((const short8*)Bpre)[fi];
    }
    if (tid < 128) biasS[tid] = biasPre[tid];
    __syncthreads();

    int wave = tid >> 6, lane = tid & 63;
    int quad = lane >> 4, mr = lane & 15;
    int rowBase = blockIdx.x * 128 + wave * 32;

    float4_ acc[2][8];
    float4_ z = {0.f, 0.f, 0.f, 0.f};
    for (int mt = 0; mt < 2; mt++)
        for (int nt = 0; nt < 8; nt++) acc[mt][nt] = z;

    for (int kt = 0; kt < 8; kt++) {
        int kk = (kt & 3) * 32 + quad * 8;
        short8 a[2];
        for (int mt = 0; mt < 2; mt++) {
            int row = rowBase + mt * 16 + mr;
            if (row >= Nrows) row = Nrows - 1;  // in-bounds; result discarded
            if (kt < 4) {
                a[mt] = *(const short8*)(Aagg + (size_t)row * 128 + kk);
            } else if (selfF32) {
                const float* p = (const float*)Aself + (size_t)row * 128 + kk;
                float4_ f0 = *(const float4_*)p;
                float4_ f1 = *(const float4_*)(p + 4);
                short8 t;
#pragma unroll
                for (int j = 0; j < 4; j++) {
                    t[j] = (short)f2bf(f0[j]);
                    t[4 + j] = (short)f2bf(f1[j]);
                }
                a[mt] = t;
            } else {
                a[mt] = *(const short8*)((const unsigned short*)Aself + (size_t)row * 128 + kk);
            }
        }
        for (int nt = 0; nt < 8; nt++) {
            short8 b = *(const short8*)(ldsB + ((size_t)(kt * 8 + nt) * 64 + lane) * 8);
            acc[0][nt] = __builtin_amdgcn_mfma_f32_16x16x32_bf16(a[0], b, acc[0][nt], 0, 0, 0);
            acc[1][nt] = __builtin_amdgcn_mfma_f32_16x16x32_bf16(a[1], b, acc[1][nt], 0, 0, 0);
        }
    }

    // C/D layout: col = lane&15, row = (lane>>4)*4 + reg
    for (int mt = 0; mt < 2; mt++) {
        for (int nt = 0; nt < 8; nt++) {
            int col = nt * 16 + mr;
            float bv = biasS[col];
            for (int r = 0; r < 4; r++) {
                int row = rowBase + mt * 16 + quad * 4 + r;
                if (row < Nrows) {
                    float v = acc[mt][nt][r] + bv;
                    if (relu) v = fmaxf(v, 0.f);
                    if (outBf16)
                        ((unsigned short*)Out)[(size_t)row * 128 + col] = f2bf(v);
                    else
                        ((float*)Out)[(size_t)row * 128 + col] = v;
                }
            }
        }
    }
}

extern "C" void kernel_launch(void* const* d_in, const int* in_sizes, int n_in,
                              void* d_out, int out_size, void* d_ws, size_t ws_size,
                              hipStream_t stream) {
    const float* x = (const float*)d_in[0];
    const int* ei = (const int*)d_in[1];
    const float* Wn1 = (const float*)d_in[2];
    const float* bn1 = (const float*)d_in[3];
    const float* Ws1 = (const float*)d_in[4];
    const float* bs1 = (const float*)d_in[5];
    const float* Wn2 = (const float*)d_in[6];
    const float* bn2 = (const float*)d_in[7];
    const float* Ws2 = (const float*)d_in[8];
    const float* bs2 = (const float*)d_in[9];

    const int N = in_sizes[0] / 128;
    const int E = in_sizes[1] / 2;
    const int* srcI = ei;
    const int* dstI = ei + E;
    const int NB = (N + 255) >> 8;  // <= NBMAX for N <= 131072

    char* ws = (char*)d_ws;
    size_t off = 0;
    auto alloc = [&](size_t bytes) -> void* {
        void* p = ws + off;
        off += (bytes + 255) & ~(size_t)255;
        return p;
    };
    int* deg = (int*)alloc((size_t)N * 4);
    int* offs = (int*)alloc((size_t)N * 4);
    int* bucketCnt = (int*)alloc((NBMAX + 1) * 4);
    int* bucketOffs = (int*)alloc((NBMAX + 1) * 4);
    int* bucketCur = (int*)alloc((NBMAX + 1) * 4);
    unsigned short* Bpre = (unsigned short*)alloc(2 * 32768 * 2);
    float* biasPre = (float*)alloc(2 * 128 * 4);
    int* sortedSrc = (int*)alloc((size_t)E * 4);
    unsigned short* Aagg = (unsigned short*)alloc((size_t)N * 128 * 2);
    size_t baseNeed = off;
    size_t bf16Buf = ((size_t)N * 128 * 2 + 255) & ~(size_t)255;
    bool bigWs = (ws_size >= baseNeed + 2 * bf16Buf);
    unsigned int* xb = nullptr;
    unsigned short* h1b = nullptr;
    if (bigWs) {
        xb = (unsigned int*)alloc((size_t)N * 128 * 2);
        h1b = (unsigned short*)alloc((size_t)N * 128 * 2);
    }
    // bucketBuf (E u32, 6.4 MB) aliases Aagg (dead until agg1)
    unsigned int* bucketBuf = (unsigned int*)Aagg;

    // ---- CSR build + overlapped wprep/cvt ----
    int ebBlocks = (E + 4095) / 4096;
    int n2 = N * 64;
    int cvtBlocks = bigWs ? (n2 + 2047) / 2048 : 0;
    hipMemsetAsync(bucketCnt, 0, (size_t)NB * 4, stream);
    bucket_count<<<ebBlocks, 256, 0, stream>>>(dstI, E, NB, bucketCnt);
    bucket_scan<<<1, 512, 0, stream>>>(bucketCnt, NB, bucketOffs, bucketCur);
    partition_wprep<<<ebBlocks + 32, 256, 0, stream>>>(
        srcI, dstI, E, NB, ebBlocks, bucketCur, bucketBuf,
        Wn1, Ws1, bn1, bs1, Wn2, Ws2, bn2, bs2, Bpre, biasPre);
    csrbuild_cvt<<<NB + cvtBlocks, 256, 0, stream>>>(bucketBuf, bucketOffs, N, NB, deg, offs,
                                                     sortedSrc, x, xb, n2);

    int aggBlocks = (N + 3) / 4;
    int gemmBlocks = (N + 127) / 128;

    if (bigWs) {
        // Layout A: all gathers bf16 (256 B/row)
        agg_bf16_kernel<<<aggBlocks, 256, 0, stream>>>(xb, deg, offs, sortedSrc,
                                                       (unsigned int*)Aagg, N);
        gemm_kernel<<<gemmBlocks, 256, 0, stream>>>(Aagg, xb, Bpre, biasPre, h1b, 1, 0, 1, N);
        agg_bf16_kernel<<<aggBlocks, 256, 0, stream>>>((const unsigned int*)h1b, deg, offs,
                                                       sortedSrc, (unsigned int*)Aagg, N);
        gemm_kernel<<<gemmBlocks, 256, 0, stream>>>(Aagg, h1b, Bpre + 32768, biasPre + 128,
                                                    d_out, 0, 0, 0, N);
    } else {
        // Layout B: f32 gathers, h1 f32 staged in d_out
        float* h1 = (float*)d_out;
        agg_f32_kernel<<<aggBlocks, 256, 0, stream>>>(x, deg, offs, sortedSrc,
                                                      (unsigned int*)Aagg, N);
        gemm_kernel<<<gemmBlocks, 256, 0, stream>>>(Aagg, x, Bpre, biasPre, h1, 1, 1, 0, N);
        agg_f32_kernel<<<aggBlocks, 256, 0, stream>>>(h1, deg, offs, sortedSrc,
                                                      (unsigned int*)Aagg, N);
        gemm_kernel<<<gemmBlocks, 256, 0, stream>>>(Aagg, h1, Bpre + 32768, biasPre + 128,
                                                    d_out, 0, 1, 0, N);
    }
}